// Round 2
// baseline (933.883 us; speedup 1.0000x reference)
//
#include <hip/hip_runtime.h>
#include <math.h>

#define NB   256   // groups (B)
#define XD   784   // X_DIM
#define ZD   32    // Z_DIM
#define NC   10    // N_CLS
#define LLEN 512   // L

__global__ __launch_bounds__(512)
void fused_hypermlp_kernel(const float* __restrict__ x,
                           const float* __restrict__ W1,
                           const float* __restrict__ b1,
                           const float* __restrict__ beta,
                           const float* __restrict__ W2,
                           const float* __restrict__ b2,
                           float* __restrict__ out)
{
    const int g    = blockIdx.x;       // group
    const int l    = threadIdx.x;      // column 0..511
    const int lane = l & 63;
    const int wid  = l >> 6;           // 0..7

    const float* xg  = x  + (size_t)g * XD * LLEN + l;
    const float* w1g = W1 + (size_t)g * ZD * XD;

    float acc[ZD];
    #pragma unroll
    for (int z = 0; z < ZD; ++z) acc[z] = 0.f;

    // ---- GEMM1: h[z][l] = sum_x W1[z][x] * x[x][l] ----
    // x loads: coalesced (lane == column). W1 loads: wave-uniform -> scalar.
    for (int xi = 0; xi < XD; xi += 8) {
        float xv[8];
        #pragma unroll
        for (int j = 0; j < 8; ++j)
            xv[j] = xg[(size_t)(xi + j) * LLEN];
        #pragma unroll
        for (int z = 0; z < ZD; ++z) {
            const float* w = w1g + z * XD + xi;
            #pragma unroll
            for (int j = 0; j < 8; ++j)
                acc[z] = fmaf(w[j], xv[j], acc[z]);
        }
    }

    // ---- bias + GroupSwish: h * sigmoid(h*softplus(beta)) / 1.1 ----
    const float sp = log1pf(expf(beta[g]));
    #pragma unroll
    for (int z = 0; z < ZD; ++z) {
        float h = acc[z] + b1[g * ZD + z];
        float s = 1.f / (1.f + expf(-h * sp));
        acc[z] = h * s * (1.0f / 1.1f);
    }

    // ---- GEMM2: o[c][l] = sum_z W2[c][z] * h[z][l] + b2[c] ----
    const float* w2g = W2 + (size_t)g * NC * ZD;
    const float* b2g = b2 + (size_t)g * NC;
    float o[NC];
    #pragma unroll
    for (int c = 0; c < NC; ++c) {
        float s = b2g[c];
        #pragma unroll
        for (int z = 0; z < ZD; ++z)
            s = fmaf(w2g[c * ZD + z], acc[z], s);
        o[c] = s;
    }

    // ---- softmax over the whole group's C*L = 5120 values ----
    __shared__ float redm[8];
    __shared__ float reds[8];

    float m = -INFINITY;
    #pragma unroll
    for (int c = 0; c < NC; ++c) m = fmaxf(m, o[c]);
    #pragma unroll
    for (int off = 32; off > 0; off >>= 1)
        m = fmaxf(m, __shfl_xor(m, off));
    if (lane == 0) redm[wid] = m;
    __syncthreads();
    if (wid == 0) {
        float v = (lane < 8) ? redm[lane] : -INFINITY;
        #pragma unroll
        for (int off = 4; off > 0; off >>= 1)
            v = fmaxf(v, __shfl_xor(v, off));
        if (lane == 0) redm[0] = v;
    }
    __syncthreads();
    const float M = redm[0];

    float e[NC];
    float ssum = 0.f;
    #pragma unroll
    for (int c = 0; c < NC; ++c) { e[c] = expf(o[c] - M); ssum += e[c]; }
    #pragma unroll
    for (int off = 32; off > 0; off >>= 1)
        ssum += __shfl_xor(ssum, off);
    if (lane == 0) reds[wid] = ssum;
    __syncthreads();
    if (wid == 0) {
        float v = (lane < 8) ? reds[lane] : 0.f;
        #pragma unroll
        for (int off = 4; off > 0; off >>= 1)
            v += __shfl_xor(v, off);
        if (lane == 0) reds[0] = v;
    }
    __syncthreads();
    const float inv = 1.f / reds[0];

    // ---- write out[g][c*L + l], coalesced per c ----
    float* og = out + (size_t)g * NC * LLEN + l;
    #pragma unroll
    for (int c = 0; c < NC; ++c)
        og[(size_t)c * LLEN] = e[c] * inv;
}

extern "C" void kernel_launch(void* const* d_in, const int* in_sizes, int n_in,
                              void* d_out, int out_size, void* d_ws, size_t ws_size,
                              hipStream_t stream) {
    const float* x    = (const float*)d_in[0];
    const float* W1   = (const float*)d_in[1];
    const float* b1   = (const float*)d_in[2];
    const float* beta = (const float*)d_in[3];
    const float* W2   = (const float*)d_in[4];
    const float* b2   = (const float*)d_in[5];
    float* out        = (float*)d_out;

    hipLaunchKernelGGL(fused_hypermlp_kernel,
                       dim3(NB), dim3(LLEN), 0, stream,
                       x, W1, b1, beta, W2, b2, out);
}